// Round 1
// baseline (619.407 us; speedup 1.0000x reference)
//
#include <hip/hip_runtime.h>

// Problem constants (fixed by setup_inputs): B=4, H=W=256, C=64, OC=64, K=3, PAD=1
#define FEAT_N (4*64*256*256)      // fp32 elements
#define OFFS_N (4*18*256*256)
#define WT_N   (9*64*64)           // deform weights transposed [k][ic][oc]
#define WT2_N  (576*20)            // offset-conv weights transposed [ic*9+t][oc pad 20]

// ---------------------------------------------------------------------------
// Weight pre-transpose (runs once per launch, trivially cheap)
// ---------------------------------------------------------------------------
__global__ __launch_bounds__(256) void prep_weights(const float* __restrict__ dw,
                                                    const float* __restrict__ ow,
                                                    float* __restrict__ wt,
                                                    float* __restrict__ wt2) {
    int idx = blockIdx.x * 256 + threadIdx.x;
    if (idx < WT_N) {
        int oc = idx & 63;
        int ic = (idx >> 6) & 63;
        int k  = idx >> 12;
        wt[idx] = dw[oc * 576 + ic * 9 + k];
    }
    int i2 = idx - WT_N;
    if (i2 >= 0 && i2 < WT2_N) {
        int t  = i2 / 20;
        int oc = i2 - t * 20;
        wt2[i2] = (oc < 18) ? ow[oc * 576 + t] : 0.f;
    }
}

// ---------------------------------------------------------------------------
// conv1: x[4,3,256,256] * w[64,3,3,3] + b -> feat[4,64,256,256], pad=1
// block = 256 threads = one w-row, 2 h-rows per block (2 pixels/thread)
// ---------------------------------------------------------------------------
__global__ __launch_bounds__(256) void conv1_kernel(const float* __restrict__ x,
                                                    const float* __restrict__ cw,
                                                    const float* __restrict__ cb,
                                                    float* __restrict__ feat) {
    __shared__ __align__(16) float wl[64 * 28];   // [oc][27 pad 28]
    __shared__ float bl[64];
    const int tid = threadIdx.x;
    for (int i = tid; i < 64 * 28; i += 256) {
        int oc = i / 28;
        int t  = i - oc * 28;
        wl[i] = (t < 27) ? cw[oc * 27 + t] : 0.f;
    }
    if (tid < 64) bl[tid] = cb[tid];
    __syncthreads();

    const int bx = blockIdx.x;
    const int b  = bx >> 7;              // 512 blocks: b in 0..3
    const int h0 = (bx & 127) << 1;      // rows h0, h0+1
    const int w  = tid;

    float xr[3][4][3];
#pragma unroll
    for (int ic = 0; ic < 3; ic++) {
#pragma unroll
        for (int r = 0; r < 4; r++) {
            int row = h0 - 1 + r;
            bool rok = (unsigned)row < 256u;
#pragma unroll
            for (int j = 0; j < 3; j++) {
                int col = w - 1 + j;
                bool ok = rok && ((unsigned)col < 256u);
                xr[ic][r][j] = ok ? x[((b * 3 + ic) << 16) + (row << 8) + col] : 0.f;
            }
        }
    }

    for (int oc = 0; oc < 64; oc++) {
        float aA = bl[oc];
        float aB = aA;
        const float* wp = &wl[oc * 28];
#pragma unroll
        for (int ic = 0; ic < 3; ic++) {
#pragma unroll
            for (int i = 0; i < 3; i++) {
#pragma unroll
                for (int j = 0; j < 3; j++) {
                    float wv = wp[ic * 9 + i * 3 + j];
                    aA += xr[ic][i][j] * wv;
                    aB += xr[ic][i + 1][j] * wv;
                }
            }
        }
        int o = ((b * 64 + oc) << 16) + (h0 << 8) + w;
        feat[o]       = aA;
        feat[o + 256] = aB;
    }
}

// ---------------------------------------------------------------------------
// conv2: feat[4,64,256,256] * ow[18,64,3,3] + ob -> offs[4,18,256,256], pad=1
// block = 256 threads, 2 rows/block, 2 pixels/thread, weights in LDS
// ---------------------------------------------------------------------------
__global__ __launch_bounds__(256) void conv2_kernel(const float* __restrict__ feat,
                                                    const float* __restrict__ wt2,
                                                    const float* __restrict__ ob,
                                                    float* __restrict__ offs) {
    __shared__ __align__(16) float w2[WT2_N];     // [ic*9+t][20]
    const int tid = threadIdx.x;
    {
        const float4* s4 = (const float4*)wt2;
        float4* d4 = (float4*)w2;
        for (int i = tid; i < WT2_N / 4; i += 256) d4[i] = s4[i];
    }
    __syncthreads();

    const int bx = blockIdx.x;
    const int b  = bx >> 7;
    const int h0 = (bx & 127) << 1;
    const int w  = tid;

    float accA[20], accB[20];
#pragma unroll
    for (int q = 0; q < 20; q++) {
        float bv = (q < 18) ? ob[q] : 0.f;
        accA[q] = bv;
        accB[q] = bv;
    }

    for (int ic = 0; ic < 64; ic++) {
        const float* fp = feat + ((size_t)(b * 64 + ic) << 16);
        float rv[4][3];
#pragma unroll
        for (int r = 0; r < 4; r++) {
            int row = h0 - 1 + r;
            bool rok = (unsigned)row < 256u;
#pragma unroll
            for (int j = 0; j < 3; j++) {
                int col = w - 1 + j;
                rv[r][j] = (rok && ((unsigned)col < 256u)) ? fp[(row << 8) + col] : 0.f;
            }
        }
        const float4* wrow = (const float4*)&w2[ic * 180];
#pragma unroll
        for (int t = 0; t < 9; t++) {
            const int i = t / 3, j = t - (t / 3) * 3;
            float fA = rv[i][j];
            float fB = rv[i + 1][j];
#pragma unroll
            for (int q = 0; q < 5; q++) {
                float4 wv = wrow[t * 5 + q];
                accA[q * 4 + 0] += fA * wv.x; accA[q * 4 + 1] += fA * wv.y;
                accA[q * 4 + 2] += fA * wv.z; accA[q * 4 + 3] += fA * wv.w;
                accB[q * 4 + 0] += fB * wv.x; accB[q * 4 + 1] += fB * wv.y;
                accB[q * 4 + 2] += fB * wv.z; accB[q * 4 + 3] += fB * wv.w;
            }
        }
    }

#pragma unroll
    for (int oc = 0; oc < 18; oc++) {
        int o = ((b * 18 + oc) << 16) + (h0 << 8) + w;
        offs[o]       = accA[oc];
        offs[o + 256] = accB[oc];
    }
}

// ---------------------------------------------------------------------------
// deform conv: per block, a 128-pixel strip (fixed b,ho) x all 64 oc.
// Per tap k: stage w_k[64ic][64oc] (16KB) + bilinear samples samp[64ic][128px]
// (32KB) in LDS, then register-tiled 8px x 4oc fp32 accumulation.
// ---------------------------------------------------------------------------
__global__ __launch_bounds__(256) void deform_kernel(const float* __restrict__ feat,
                                                     const float* __restrict__ offs,
                                                     const float* __restrict__ wt,
                                                     const float* __restrict__ db,
                                                     float* __restrict__ out) {
    __shared__ __align__(16) float samp[64 * 128];  // [ic][px]
    __shared__ __align__(16) float wk[64 * 64];     // [ic][oc]
    const int tid = threadIdx.x;
    const int bx  = blockIdx.x;
    const int wo_base = (bx & 1) << 7;
    const int ho  = (bx >> 1) & 255;
    const int b   = bx >> 9;

    const int pxt = tid & 15;        // 8 pixels each: px = pxt*8 + pi
    const int oct = tid >> 4;        // 4 ocs each:    oc = oct*4 + q
    const int px  = tid & 127;       // sampling role
    const int half = tid >> 7;       // ic half (0..1) -> 32 ic each

    const int wo = wo_base + px;

    float acc[8][4];
#pragma unroll
    for (int pi = 0; pi < 8; pi++)
#pragma unroll
        for (int q = 0; q < 4; q++) acc[pi][q] = 0.f;

    const float* fb = feat + ((size_t)(b * 64 + half * 32) << 16);
    const float4* wt4   = (const float4*)wt;
    float4* wk4w        = (float4*)wk;
    const float4* wk4   = (const float4*)wk;
    const float4* samp4 = (const float4*)samp;

    for (int k = 0; k < 9; k++) {
        // --- per-thread coords for sampling role (px, tap k) ---
        int ky = k / 3;
        int kx = k - ky * 3;
        float offy = offs[((b * 18 + 2 * k) << 16) + (ho << 8) + wo];
        float offx = offs[((b * 18 + 2 * k + 1) << 16) + (ho << 8) + wo];
        float sy = (float)(ho - 1 + ky) + offy;
        float sx = (float)(wo - 1 + kx) + offx;
        float y0f = floorf(sy), x0f = floorf(sx);
        float dy = sy - y0f, dx = sx - x0f;
        int y0 = (int)y0f, x0 = (int)x0f;
        bool vy0 = (unsigned)y0 < 256u;
        bool vy1 = (unsigned)(y0 + 1) < 256u;
        bool vx0 = (unsigned)x0 < 256u;
        bool vx1 = (unsigned)(x0 + 1) < 256u;
        int yi0 = y0 < 0 ? 0 : (y0 > 255 ? 255 : y0);
        int yi1 = (y0 + 1) < 0 ? 0 : ((y0 + 1) > 255 ? 255 : (y0 + 1));
        int xi0 = x0 < 0 ? 0 : (x0 > 255 ? 255 : x0);
        int xi1 = (x0 + 1) < 0 ? 0 : ((x0 + 1) > 255 ? 255 : (x0 + 1));
        float w00 = (1.f - dy) * (1.f - dx); if (!(vy0 && vx0)) w00 = 0.f;
        float w01 = (1.f - dy) * dx;         if (!(vy0 && vx1)) w01 = 0.f;
        float w10 = dy * (1.f - dx);         if (!(vy1 && vx0)) w10 = 0.f;
        float w11 = dy * dx;                 if (!(vy1 && vx1)) w11 = 0.f;
        int a00 = (yi0 << 8) + xi0, a01 = (yi0 << 8) + xi1;
        int a10 = (yi1 << 8) + xi0, a11 = (yi1 << 8) + xi1;

        __syncthreads();   // previous tap's accumulate reads are done

        // --- stage w_k[ic][oc] (contiguous copy from pre-transposed wt) ---
#pragma unroll
        for (int i = 0; i < 4; i++)
            wk4w[tid + 256 * i] = wt4[k * 1024 + tid + 256 * i];

        // --- bilinear sampling: 32 channels per thread, lanes over pixels ---
#pragma unroll 4
        for (int i = 0; i < 32; i++) {
            const float* fp = fb + ((size_t)i << 16);
            float g = w00 * fp[a00] + w01 * fp[a01] + w10 * fp[a10] + w11 * fp[a11];
            samp[(half * 32 + i) * 128 + px] = g;
        }
        __syncthreads();

        // --- accumulate: 8px x 4oc per thread ---
#pragma unroll
        for (int ic = 0; ic < 64; ic++) {
            float4 s0 = samp4[ic * 32 + pxt * 2];
            float4 s1 = samp4[ic * 32 + pxt * 2 + 1];
            float4 wv = wk4[ic * 16 + oct];
            float s[8] = {s0.x, s0.y, s0.z, s0.w, s1.x, s1.y, s1.z, s1.w};
            float wq[4] = {wv.x, wv.y, wv.z, wv.w};
#pragma unroll
            for (int pi = 0; pi < 8; pi++)
#pragma unroll
                for (int q = 0; q < 4; q++) acc[pi][q] += s[pi] * wq[q];
        }
    }

    // --- epilogue: bias + coalesced float4 stores ---
#pragma unroll
    for (int q = 0; q < 4; q++) {
        int oc = oct * 4 + q;
        float bv = db[oc];
        float* op = out + ((size_t)(b * 64 + oc) << 16) + (ho << 8) + wo_base + pxt * 8;
        float4 v0 = {acc[0][q] + bv, acc[1][q] + bv, acc[2][q] + bv, acc[3][q] + bv};
        float4 v1 = {acc[4][q] + bv, acc[5][q] + bv, acc[6][q] + bv, acc[7][q] + bv};
        *(float4*)op = v0;
        *(float4*)(op + 4) = v1;
    }
}

// ---------------------------------------------------------------------------
extern "C" void kernel_launch(void* const* d_in, const int* in_sizes, int n_in,
                              void* d_out, int out_size, void* d_ws, size_t ws_size,
                              hipStream_t stream) {
    const float* x  = (const float*)d_in[0];
    const float* cw = (const float*)d_in[1];
    const float* cb = (const float*)d_in[2];
    const float* ow = (const float*)d_in[3];
    const float* ob = (const float*)d_in[4];
    const float* dw = (const float*)d_in[5];
    const float* db = (const float*)d_in[6];
    float* out = (float*)d_out;

    float* feat = (float*)d_ws;                  // 64 MB
    float* offsb = feat + FEAT_N;                // 18 MB
    float* wt   = offsb + OFFS_N;                // 144 KB
    float* wt2  = wt + WT_N;                     // 45 KB

    prep_weights<<<189, 256, 0, stream>>>(dw, ow, wt, wt2);
    conv1_kernel<<<512, 256, 0, stream>>>(x, cw, cb, feat);
    conv2_kernel<<<512, 256, 0, stream>>>(feat, wt2, ob, offsb);
    deform_kernel<<<2048, 256, 0, stream>>>(feat, offsb, wt, db, out);
}